// Round 1
// 3018.458 us; speedup vs baseline: 1.0883x; 1.0883x over previous
//
#include <hip/hip_runtime.h>
#include <cstdint>

// CharRNN fused kernel, round 5 — MI355X (gfx950).
//
// Topology: 8 clusters x 16 members = 128 wgs. Cluster c owns batch rows
// [16c,16c+16). Member m owns hidden outputs [32m,32m+32) (W_hh bf16 hi+lo
// register-resident) and vocab rows [8m,8m+8) of W_fc (k split, waves 2/3).
//
// Round-5 exchange (r4 was counter-RMW-gated + fixed-point tags + reader-side
// hi/lo split = ~7.7k cy/step; the 32 serialized same-line atomicAdds, the
// missing release ordering (counter could beat data -> retry sweeps) and
// ~300 VALU unpack insts/thread/step dominated):
//  - writers publish h as (hi bf16 | lo bf16) packed u32, ALREADY in MFMA
//    fragment order (lane-pair shuffle packs adjacent-j pairs). RNE split of
//    full fp32 h — numerics equal or better than r4's 21-bit fixed point.
//  - release: per-WAVE flag. s_waitcnt vmcnt(0) (sc1 stores acked at the
//    coherence point) then an independent flag store — 32 independent flag
//    stores per cluster-step instead of a serialized RMW chain.
//  - readers spin on ONE 128B flag line (flags[lane&31], __all >= t), then
//    sweep 32 coalesced dwords/thread and ds_write_b32 them straight into
//    LDS (stride-1, conflict-free). Zero unpack VALU, zero retries.

typedef short bf16x8 __attribute__((ext_vector_type(8)));
typedef float f32x4 __attribute__((ext_vector_type(4)));

#define VOCAB 128
#define EMB   16
#define HID   512
#define TT    1024
#define NCL   8      // clusters
#define BB    16     // batch rows per cluster
#define JC    32     // hidden outputs per member
#define NWG   128
#define CLW   8192               // dwords per cluster per gen (hi 4096 + lo 4096)
#define BUFW  (NCL * CLW)        // 65536 dwords per generation buffer
#define FLAGOFF (2 * BUFW)       // u32 index of flag region (8 x 32 u32)
#define PJC   33                 // padded ep stride

__device__ __forceinline__ unsigned short f2bf(float f) {
  uint32_t u = __builtin_bit_cast(uint32_t, f);
  u += 0x7FFFu + ((u >> 16) & 1u);
  return (unsigned short)(u >> 16);
}
__device__ __forceinline__ float bf2f(unsigned short s) {
  uint32_t u = (uint32_t)s << 16;
  return __builtin_bit_cast(float, u);
}
__device__ __forceinline__ float ftanh(float z) {
  z = fminf(15.f, fmaxf(-15.f, z));
  float e = __expf(2.f * z);
  return (e - 1.f) * __builtin_amdgcn_rcpf(e + 1.f);
}
__device__ __forceinline__ uint32_t aload(const uint32_t* p) {
  return __hip_atomic_load(p, __ATOMIC_RELAXED, __HIP_MEMORY_SCOPE_AGENT);
}
__device__ __forceinline__ void astore(uint32_t* p, uint32_t v) {
  __hip_atomic_store(p, v, __ATOMIC_RELAXED, __HIP_MEMORY_SCOPE_AGENT);
}

__global__ __launch_bounds__(256, 1) void charrnn_kernel(
    const int* __restrict__ xin,
    const float* __restrict__ emb,
    const float* __restrict__ wih,
    const float* __restrict__ whh,
    const float* __restrict__ bih,
    const float* __restrict__ bhh,
    const float* __restrict__ wfc,
    const float* __restrict__ bfc,
    float* __restrict__ out,
    uint32_t* __restrict__ hx)
{
  // frag-order h state: idx = ks*512 + lane*8 + j  (lane = quad_k*16 + row)
  __shared__ __align__(16) unsigned short a_hi[16 * 512];   // 16 KB
  __shared__ __align__(16) unsigned short a_lo[16 * 512];   // 16 KB
  __shared__ float ep[VOCAB * PJC];                         // 16.9 KB
  __shared__ unsigned char xtok[BB * TT];                   // 16 KB
  __shared__ __align__(16) float red[2][256];               // 2 KB logits partials

  const int tid  = threadIdx.x;
  const int wave = tid >> 6;
  const int lane = tid & 63;
  const int col  = lane & 15;
  const int quad = lane >> 4;
  const int cl   = blockIdx.x & 7;   // members of a cluster share blockIdx mod 8
  const int m    = blockIdx.x >> 3;  // -> same XCD under round-robin (perf hint)

  // ---- weight fragments -> registers (global gather, one-time) ----
  bf16x8 wfh[16], wfl[16], wfcf[8];
  if (wave < 2) {
    const int nrow = m * JC + wave * 16 + col;
    const float* wr = whh + (size_t)nrow * HID + quad * 8;
    #pragma unroll
    for (int ks = 0; ks < 16; ++ks) {
      bf16x8 hi, lo;
      #pragma unroll
      for (int j = 0; j < 8; ++j) {
        float w = wr[ks * 32 + j];
        unsigned short h = f2bf(w);
        hi[j] = (short)h;
        lo[j] = (short)f2bf(w - bf2f(h));
      }
      wfh[ks] = hi; wfl[ks] = lo;
    }
  } else {
    const int vrow = m * 8 + (col & 7);
    const float* wr = wfc + (size_t)vrow * HID + (wave - 2) * 256 + quad * 8;
    #pragma unroll
    for (int ks = 0; ks < 8; ++ks) {
      bf16x8 f;
      #pragma unroll
      for (int j = 0; j < 8; ++j) f[j] = (short)f2bf(wr[ks * 32 + j]);
      wfcf[ks] = f;
    }
  }
  const float bfcr = bfc[m * 8 + (col & 7)];

  // ---- LDS init: h0 = 0, ep table, tokens ----
  for (int i = tid; i < 16 * 512; i += 256) { a_hi[i] = 0; a_lo[i] = 0; }
  for (int i = tid; i < VOCAB * JC; i += 256) {
    int v = i >> 5, jl = i & 31;
    int jg = m * JC + jl;
    float s = bih[jg] + bhh[jg];
    #pragma unroll
    for (int e = 0; e < EMB; ++e) s += emb[v * EMB + e] * wih[jg * EMB + e];
    ep[v * PJC + jl] = s;
  }
  for (int i = tid; i < BB * TT; i += 256) {
    int b = i >> 10, t = i & 1023;
    xtok[i] = (unsigned char)xin[(cl * BB + b) * TT + t];
  }
  __syncthreads();

  // ---- main time loop ----
  uint32_t* const flags = hx + FLAGOFF + cl * 32;   // one 128B line per cluster
  f32x4 prev_lacc = {0.f, 0.f, 0.f, 0.f};

  #pragma unroll 1
  for (int t = 0; t <= TT + 1; ++t) {
    const int par = t & 1;

    // -- phase A: logits partials (computed in prior C) to LDS --
    if (wave >= 2 && t >= 2) {
      *(f32x4*)&red[wave - 2][lane * 4] = prev_lacc;
    }

    // -- phase B: flag gate, then coalesced sweep straight into LDS --
    if (t >= 1 && t <= TT) {
      uint32_t f;
      do {
        f = aload(&flags[lane & 31]);
      } while (__all((int)(f >= (uint32_t)t)) == 0);
      asm volatile("" ::: "memory");   // keep sweep loads after the gate

      const uint32_t* src = hx + par * BUFW + cl * CLW + tid;
      uint32_t v[32];
      #pragma unroll
      for (int i = 0; i < 32; ++i) v[i] = aload(src + 256 * i);
      #pragma unroll
      for (int i = 0; i < 16; ++i)
        *(uint32_t*)&a_hi[(tid + 256 * i) * 2] = v[i];
      #pragma unroll
      for (int i = 0; i < 16; ++i)
        *(uint32_t*)&a_lo[(tid + 256 * i) * 2] = v[16 + i];
    }
    __syncthreads();  // B1: lds_a(gen t) ready; red stored

    // -- phase C --
    if (wave < 2) {
      // recurrence: gen t -> gen t+1 (3-term hi/lo MFMA), publish + flag
      if (t < TT) {
        f32x4 acc0 = {0.f,0.f,0.f,0.f}, acc1 = {0.f,0.f,0.f,0.f}, acc2 = {0.f,0.f,0.f,0.f};
        #pragma unroll
        for (int ks = 0; ks < 16; ++ks) {
          bf16x8 ah = *(const bf16x8*)&a_hi[ks * 512 + lane * 8];
          bf16x8 al = *(const bf16x8*)&a_lo[ks * 512 + lane * 8];
          acc0 = __builtin_amdgcn_mfma_f32_16x16x32_bf16(ah, wfh[ks], acc0, 0, 0, 0);
          acc1 = __builtin_amdgcn_mfma_f32_16x16x32_bf16(al, wfh[ks], acc1, 0, 0, 0);
          acc2 = __builtin_amdgcn_mfma_f32_16x16x32_bf16(ah, wfl[ks], acc2, 0, 0, 0);
        }
        const int jl = wave * 16 + col;
        // frag-order global dest: ks = m; qk = wave*2 + (col>>3); j = col&7.
        // even lanes store hi-pairs, odd lanes store lo-pairs (lane^1 shuffle).
        uint32_t* wb = hx + ((t + 1) & 1) * BUFW + cl * CLW
                     + ((lane & 1) ? 4096 : 0)
                     + m * 256 + (wave * 2 + (col >> 3)) * 64 + ((col & 7) >> 1);
        #pragma unroll
        for (int i = 0; i < 4; ++i) {
          const int b = quad * 4 + i;
          float z = acc0[i] + acc1[i] + acc2[i]
                  + ep[(int)xtok[b * TT + t] * PJC + jl];
          float h = ftanh(z);
          unsigned short hi = f2bf(h);
          float lof = h - bf2f(hi);
          unsigned short lo = f2bf(lof);
          uint32_t pk = (uint32_t)hi | ((uint32_t)lo << 16);
          uint32_t pp = (uint32_t)__shfl_xor((int)pk, 1);
          uint32_t word = (lane & 1) ? ((pp >> 16) | (pk & 0xFFFF0000u))
                                     : ((pk & 0xFFFFu) | (pp << 16));
          astore(wb + b * 4, word);
        }
        // release: sc1 stores acked at the coherence point, then flag.
        asm volatile("s_waitcnt vmcnt(0)" ::: "memory");
        if (lane == 0) astore(&flags[m * 2 + wave], (uint32_t)(t + 1));
      }
    } else {
      // reduce + store logits for time t-2 (wave 2; partials in red from A)
      if (wave == 2 && t >= 2 && col < 8) {
        #pragma unroll
        for (int i = 0; i < 4; ++i) {
          const int b = quad * 4 + i;
          float s = red[0][lane * 4 + i] + red[1][lane * 4 + i] + bfcr;
          out[((size_t)(cl * BB + b) * TT + (t - 2)) * VOCAB + m * 8 + col] = s;
        }
      }
      // logits MFMA for time t-1 (k-half per wave, hi+lo terms)
      if (t >= 1 && t <= TT) {
        f32x4 lacc = {0.f, 0.f, 0.f, 0.f};
        const int kb = (wave - 2) * 8;
        #pragma unroll
        for (int ks = 0; ks < 8; ++ks) {
          bf16x8 ah = *(const bf16x8*)&a_hi[(kb + ks) * 512 + lane * 8];
          bf16x8 al = *(const bf16x8*)&a_lo[(kb + ks) * 512 + lane * 8];
          lacc = __builtin_amdgcn_mfma_f32_16x16x32_bf16(ah, wfcf[ks], lacc, 0, 0, 0);
          lacc = __builtin_amdgcn_mfma_f32_16x16x32_bf16(al, wfcf[ks], lacc, 0, 0, 0);
        }
        prev_lacc = lacc;
      }
    }
    __syncthreads();  // B2: lds_a consumed; red consumed
  }
}

extern "C" void kernel_launch(void* const* d_in, const int* in_sizes, int n_in,
                              void* d_out, int out_size, void* d_ws, size_t ws_size,
                              hipStream_t stream) {
  (void)in_sizes; (void)n_in; (void)out_size;
  if (ws_size < (size_t)FLAGOFF * sizeof(uint32_t) + 4096) return;  // 512 KB + flags

  const int*   x    = (const int*)d_in[0];
  const float* embp = (const float*)d_in[1];
  const float* W_ih = (const float*)d_in[2];
  const float* W_hh = (const float*)d_in[3];
  const float* b_ih = (const float*)d_in[4];
  const float* b_hh = (const float*)d_in[5];
  const float* W_fc = (const float*)d_in[6];
  const float* b_fc = (const float*)d_in[7];

  // zero the per-cluster flag lines (8 x 32 u32); data region needs no init
  // (flag protocol guarantees gen-t data written this run before any read)
  hipMemsetAsync((uint32_t*)d_ws + FLAGOFF, 0, NCL * 32 * sizeof(uint32_t), stream);

  charrnn_kernel<<<NWG, 256, 0, stream>>>(x, embp, W_ih, W_hh, b_ih, b_hh, W_fc, b_fc,
                                          (float*)d_out, (uint32_t*)d_ws);
}